// Round 2
// baseline (612.774 us; speedup 1.0000x reference)
//
#include <hip/hip_runtime.h>

#define F 64          // feature dim (known from reference)
#define EPW 128       // edges per wave

// Detect whether idx arrays are int64 or int32.
// Read first 256 elements as int64: if the data is really int32, the high
// 32 bits of each "int64" is the NEXT random index (>=1 w.p. 1-1/50000 each),
// so at least one read will be >= 2^32. If data is true int64 (values all
// < 50000), every read is < 2^32.
__global__ void detect_idx64(const void* __restrict__ idx_j, int n_edges,
                             int* __restrict__ flag) {
    const unsigned long long* p = (const unsigned long long*)idx_j;
    int n = n_edges < 256 ? n_edges : 256;
    int is64 = 1;
    for (int k = 0; k < n; ++k) {
        if (p[k] >= (1ull << 32)) { is64 = 0; break; }
    }
    *flag = is64;
}

__global__ __launch_bounds__(256) void cfconv_kernel(
    const float* __restrict__ x,
    const float* __restrict__ Wij,
    const void* __restrict__ idx_i_raw,
    const void* __restrict__ idx_j_raw,
    float* __restrict__ y,
    const int* __restrict__ flag,
    int n_edges)
{
    const int gwave = (int)((blockIdx.x * blockDim.x + threadIdx.x) >> 6);
    const int lane  = threadIdx.x & 63;          // lane = feature index
    const long long e0 = (long long)gwave * EPW;
    if (e0 >= n_edges) return;
    const long long e1 = (e0 + EPW < n_edges) ? e0 + EPW : n_edges;

    float acc = 0.0f;

    if (*flag) {   // ---- int64 indices ----
        const long long* ii = (const long long*)idx_i_raw;
        const long long* jj = (const long long*)idx_j_raw;
        int cur_i = (int)ii[e0];
        for (long long e = e0; e < e1; ++e) {
            const int i = (int)ii[e];
            const int j = (int)jj[e];
            if (i != cur_i) {                    // wave-uniform (idx_i sorted)
                atomicAdd(&y[(long long)cur_i * F + lane], acc);
                acc   = 0.0f;
                cur_i = i;
            }
            acc = fmaf(x[(long long)j * F + lane], Wij[e * (long long)F + lane], acc);
        }
        atomicAdd(&y[(long long)cur_i * F + lane], acc);
    } else {       // ---- int32 indices ----
        const int* ii = (const int*)idx_i_raw;
        const int* jj = (const int*)idx_j_raw;
        int cur_i = ii[e0];
        for (long long e = e0; e < e1; ++e) {
            const int i = ii[e];
            const int j = jj[e];
            if (i != cur_i) {
                atomicAdd(&y[(long long)cur_i * F + lane], acc);
                acc   = 0.0f;
                cur_i = i;
            }
            acc = fmaf(x[(long long)j * F + lane], Wij[e * (long long)F + lane], acc);
        }
        atomicAdd(&y[(long long)cur_i * F + lane], acc);
    }
}

extern "C" void kernel_launch(void* const* d_in, const int* in_sizes, int n_in,
                              void* d_out, int out_size, void* d_ws, size_t ws_size,
                              hipStream_t stream) {
    const float* x    = (const float*)d_in[0];
    const float* Wij  = (const float*)d_in[1];
    const void*  ii   = d_in[2];
    const void*  jj   = d_in[3];
    float*       y    = (float*)d_out;
    int*         flag = (int*)d_ws;
    const int n_edges = in_sizes[2];             // idx_i element count

    // zero the output (harness poisons it to 0xAA before every launch)
    hipMemsetAsync(d_out, 0, (size_t)out_size * sizeof(float), stream);
    detect_idx64<<<1, 1, 0, stream>>>(jj, n_edges, flag);

    const int n_waves  = (n_edges + EPW - 1) / EPW;
    const int n_blocks = (n_waves + 3) / 4;      // 4 waves (256 threads) per block
    cfconv_kernel<<<n_blocks, 256, 0, stream>>>(x, Wij, ii, jj, y, flag, n_edges);
}

// Round 3
// 452.227 us; speedup vs baseline: 1.3550x; 1.3550x over previous
//
#include <hip/hip_runtime.h>

#define F   64        // feature dim (known from reference)
#define EPW 160       // edges/wave: ceil(1.25M/160)=7813 waves -> one residency round
#define CH  8         // gathers in flight per chunk

// Detect whether idx arrays are int64 or int32 (wave-parallel).
// Read elements as u64: if data is really int32, the high 32 bits of each
// "u64" is the next random index (>=1 w.p. 1-1/50000 each) -> some value
// >= 2^32. True int64 data (< 50000) never exceeds 2^32.
__global__ void detect_idx64(const unsigned long long* __restrict__ p,
                             int n_edges, int* __restrict__ flag) {
    const int t = threadIdx.x;                     // 64 threads
    int n = n_edges / 2; if (n > 256) n = 256;     // safe for both dtypes
    bool big = false;
    for (int k = 0; k < 4; ++k) {
        int id = t * 4 + k;
        if (id < n) big |= (p[id] >= (1ull << 32));
    }
    unsigned long long mask = __ballot(big);
    if (t == 0) *flag = (mask == 0ull) ? 1 : 0;
}

__global__ __launch_bounds__(256, 8) void cfconv_kernel(
    const float* __restrict__ x,
    const float* __restrict__ Wij,
    const void* __restrict__ idx_i_raw,
    const void* __restrict__ idx_j_raw,
    float* __restrict__ y,
    const int* __restrict__ flag,
    int n_edges)
{
    const int gwave = (int)((blockIdx.x * blockDim.x + threadIdx.x) >> 6);
    const int lane  = threadIdx.x & 63;            // lane = feature index
    const long long e0 = (long long)gwave * EPW;
    if (e0 >= n_edges) return;
    const int cnt = (int)((e0 + EPW <= n_edges) ? EPW : (n_edges - e0));

    // ---- preload this wave's indices: lane L holds edge e0 + r*64 + L ----
    int iv[3], jv[3];
    if (*flag) {                                   // int64 indices
        const long long* ii = (const long long*)idx_i_raw;
        const long long* jj = (const long long*)idx_j_raw;
        #pragma unroll
        for (int r = 0; r < 3; ++r) {
            int p = r * 64 + lane;
            if (p < cnt) { iv[r] = (int)ii[e0 + p]; jv[r] = (int)jj[e0 + p]; }
            else         { iv[r] = -1;              jv[r] = 0; }
        }
    } else {                                       // int32 indices
        const int* ii = (const int*)idx_i_raw;
        const int* jj = (const int*)idx_j_raw;
        #pragma unroll
        for (int r = 0; r < 3; ++r) {
            int p = r * 64 + lane;
            if (p < cnt) { iv[r] = ii[e0 + p]; jv[r] = jj[e0 + p]; }
            else         { iv[r] = -1;         jv[r] = 0; }
        }
    }

    float acc   = 0.0f;
    int   cur_i = __shfl(iv[0], 0);                // first segment id (cnt >= 1)

    #pragma unroll
    for (int r = 0; r < 3; ++r) {                  // 64-edge groups (static reg idx)
        const int gbase = r * 64;
        if (gbase >= cnt) break;
        for (int c = 0; c < 8; ++c) {              // 8 chunks of CH=8 edges
            const int base = gbase + c * CH;
            if (base >= cnt) break;

            float xv[CH], wv[CH]; int ic[CH];
            #pragma unroll
            for (int k = 0; k < CH; ++k) {         // issue all loads first
                const int p   = base + k;
                const int src = p & 63;
                const int j   = __shfl(jv[r], src);
                ic[k]         = __shfl(iv[r], src);
                if (p < cnt) {
                    xv[k] = x[(long long)j * F + lane];
                    wv[k] = Wij[(e0 + p) * (long long)F + lane];
                } else { xv[k] = 0.0f; wv[k] = 0.0f; }   // ic[k] = -1 via iv pad
            }
            #pragma unroll
            for (int k = 0; k < CH; ++k) {         // then accumulate + rare flush
                if (ic[k] >= 0 && ic[k] != cur_i) {
                    atomicAdd(&y[(long long)cur_i * F + lane], acc);
                    acc = 0.0f; cur_i = ic[k];
                }
                acc = fmaf(xv[k], wv[k], acc);
            }
        }
    }
    atomicAdd(&y[(long long)cur_i * F + lane], acc);
}

extern "C" void kernel_launch(void* const* d_in, const int* in_sizes, int n_in,
                              void* d_out, int out_size, void* d_ws, size_t ws_size,
                              hipStream_t stream) {
    const float* x    = (const float*)d_in[0];
    const float* Wij  = (const float*)d_in[1];
    const void*  ii   = d_in[2];
    const void*  jj   = d_in[3];
    float*       y    = (float*)d_out;
    int*         flag = (int*)d_ws;
    const int n_edges = in_sizes[2];               // idx_i element count

    hipMemsetAsync(d_out, 0, (size_t)out_size * sizeof(float), stream);
    detect_idx64<<<1, 64, 0, stream>>>((const unsigned long long*)jj, n_edges, flag);

    const int n_waves  = (n_edges + EPW - 1) / EPW;
    const int n_blocks = (n_waves + 3) / 4;        // 4 waves (256 threads) / block
    cfconv_kernel<<<n_blocks, 256, 0, stream>>>(x, Wij, ii, jj, y, flag, n_edges);
}